// Round 14
// baseline (85.945 us; speedup 1.0000x reference)
//
#include <hip/hip_runtime.h>
#include <hip/hip_bf16.h>

#define NS     32768
#define NROWS  2048
#define HOP    127
#define NW     257
#define NB     128
#define WTILE  16
#define NST    18             // padded sub-tiles: 3 phases x 6 (st17 fully invalid)
#define PST    6              // sub-tiles per phase
#define TB1    (WTILE * HOP * 4)      // byte stride between sub-tile bases
#define TWOPI_255 0.02463994236f      // 2*pi/255

typedef _Float16 f16;
typedef __attribute__((ext_vector_type(2))) _Float16 f16x2;
typedef __attribute__((ext_vector_type(4))) _Float16 f16x4;
typedef __attribute__((ext_vector_type(8))) _Float16 f16x8;
typedef __attribute__((ext_vector_type(4))) float f32x4;

__device__ inline f32x4 load4u(const char* p) {  // 4B-aligned 16B load
    f32x4 v;
    __builtin_memcpy(&v, p, 16);
    return v;
}

// ---------------------------------------------------------------------------
// Kernel 1: folded-DFT basis table (64 KB) in fragment order (as round 8).
// ---------------------------------------------------------------------------
__global__ __launch_bounds__(256)
void basis_kernel(f16* __restrict__ bt) {
    const int t  = blockIdx.x * 256 + threadIdx.x;   // 0..4095
    const int fi = t >> 6;
    const int l  = t & 63;
    const int cq = fi >> 3;
    const int nt = (fi >> 2) & 1;
    const int kk = fi & 3;
    const int is_sin = cq >> 2;
    const int f  = (cq & 3) * 32 + nt * 16 + (l & 15);   // freq 0..127
    int m = (f * (kk * 32 + (l >> 4) * 8)) % 255;
    f16x8 v;
    #pragma unroll
    for (int j = 0; j < 8; ++j) {
        const float ang = (float)m * TWOPI_255;
        v[j] = (f16)(is_sin ? __sinf(ang) : __cosf(ang));
        m += f; if (m >= 255) m -= 255;
    }
    *(f16x8*)(bt + (size_t)t * 8) = v;   // 16B/thread, coalesced
}

// ---------------------------------------------------------------------------
// Kernel 2: one block (8 waves, 512 thr) per row; wave cq owns 32 comps
// (bfrag = 32 VGPR). PHASE-SEPARATED schedule: 3 phases x 6 sub-tiles.
// Phase = { batch-fold 6 sub-tiles -> LDS (48 KB) ; issue next phase's 12
// global loads ; barrier ; PURE MFMA stretch (24 ds_read + 48 MFMA, no folds,
// no barriers, fully unrolled) ; barrier }. 5 barriers/row vs r10's 9; loads
// stay in flight across the MFMA stretch (lgkm-only drains at barriers).
// K folded 255->128: y+[k]=x[k]+x[255-k] (cos), y-[k]=x[k]-x[255-k] (sin).
// S[f] = (sum_w Ccos^2 + Csin^2)/257.
// ---------------------------------------------------------------------------
__global__ __launch_bounds__(512, 4)
void psd_kernel(const float* __restrict__ X, const f16* __restrict__ bt,
                float* __restrict__ out) {
    const int row  = blockIdx.x;
    const int tid  = threadIdx.x;
    const int lane = tid & 63;
    const int cq   = tid >> 6;      // wave 0..7
    const int r16  = lane & 15;
    const int kg   = lane >> 4;
    const int is_sin = cq >> 2;     // waves 4..7 -> sin half

    __shared__ alignas(16) f16 ftile[PST][WTILE * 256];  // 48 KB, XOR-swizzled
    __shared__ float scol[256];

    const char* __restrict__ xrow = (const char*)(X + (size_t)row * NS);

    const int sw  = tid >> 5;           // staging window 0..15 within sub-tile
    const int sq  = tid & 31;           // staging k-quad 0..31

    // loop-invariant per-lane global byte offsets (sub-tile-local)
    const uint voff_f = (uint)((sw * HOP + sq * 4) * 4);
    const uint voff_r = (uint)((sw * HOP + 252 - sq * 4) * 4);
    const uint vclamp = (uint)((NS - 4) * 4);   // max safe 16B-load byte offset

    f32x4 fv[PST], rv[PST];             // 48 VGPR staging (static indices only)

    auto issue_loads = [&](int p) {
        #pragma unroll
        for (int s = 0; s < PST; ++s) {
            const uint tb = (uint)((p * PST + s) * TB1);
            fv[s] = load4u(xrow + min(voff_f + tb, vclamp));
            rv[s] = load4u(xrow + min(voff_r + tb, vclamp));
        }
    };

    // ---- phase-0 loads first (longest latency cover) ----
    issue_loads(0);

    // ---- basis fragments: 8 coalesced dwordx4 (table L2-resident) ----
    f16x8 bfrag[2][4];
    {
        const char* bp = (const char*)bt + (uint)(cq * 8192 + lane * 16);
        #pragma unroll
        for (int nt = 0; nt < 2; ++nt)
            #pragma unroll
            for (int kk = 0; kk < 4; ++kk)
                bfrag[nt][kk] = *(const f16x8*)(bp + (uint)((nt * 4 + kk) * 1024));
    }

    // hoisted LDS byte offsets (rd derived by XOR: base bits 6-7 zero, swizzle
    // has no bit 7, so base^(kk<<6)^rswz == (base+kk*64)^rswz)
    const uint swz  = (uint)((sw & 7) << 4);
    const uint wr_p = ((uint)(sw * 512 + sq * 8)) ^ swz;         // y+ (8B)
    const uint wr_m = ((uint)(sw * 512 + sq * 8 + 256)) ^ swz;   // y- (8B)
    const uint rd0  = ((uint)(r16 * 512 + is_sin * 256 + kg * 16))
                    ^ ((uint)((r16 & 7) << 4));

    // ---- packed fold (4 pairs) + 2 x ds_write_b64 ----
    auto fold_write = [&](f32x4 f4, f32x4 r4, char* wp, bool valid) {
        // partner of k=sq*4+j is r4[3-j]
        const f16x2 fp01 = __builtin_bit_cast(f16x2, __builtin_amdgcn_cvt_pkrtz(f4[0], f4[1]));
        const f16x2 fp23 = __builtin_bit_cast(f16x2, __builtin_amdgcn_cvt_pkrtz(f4[2], f4[3]));
        const f16x2 rp01 = __builtin_bit_cast(f16x2, __builtin_amdgcn_cvt_pkrtz(r4[3], r4[2]));
        const f16x2 rp23 = __builtin_bit_cast(f16x2, __builtin_amdgcn_cvt_pkrtz(r4[1], r4[0]));
        const f16x2 yp01 = fp01 + rp01, yp23 = fp23 + rp23;
        const f16x2 ym01 = fp01 - rp01, ym23 = fp23 - rp23;
        f16x4 h0, h1;
        h0[0] = yp01[0]; h0[1] = yp01[1]; h0[2] = yp23[0]; h0[3] = yp23[1];
        h1[0] = ym01[0]; h1[1] = ym01[1]; h1[2] = ym23[0]; h1[3] = ym23[1];
        if (sq == 0) { h0[0] = (f16)f4[0]; h1[0] = (f16)0.0f; }  // k=0: pad partner
        if (!valid) {
            #pragma unroll
            for (int j = 0; j < 4; ++j) { h0[j] = (f16)0.0f; h1[j] = (f16)0.0f; }
        }
        *(f16x4*)(wp + wr_p) = h0;
        *(f16x4*)(wp + wr_m) = h1;
    };

    auto fold_phase = [&](int p) {
        #pragma unroll
        for (int s = 0; s < PST; ++s) {
            const int w0 = (p * PST + s) * WTILE + sw;
            fold_write(fv[s], rv[s], (char*)&ftile[s][0], w0 < NW);
        }
    };

    float ssum0 = 0.f, ssum1 = 0.f, ssum2 = 0.f, ssum3 = 0.f;

    auto mfma_phase = [&]() {
        __builtin_amdgcn_s_setprio(1);
        #pragma unroll
        for (int s = 0; s < PST; ++s) {
            const char* ap = (const char*)&ftile[s][0];
            f32x4 a0 = {0,0,0,0}, a1 = {0,0,0,0};
            #pragma unroll
            for (int kk = 0; kk < 4; ++kk) {
                const f16x8 af = *(const f16x8*)(ap + (rd0 ^ (uint)(kk << 6)));
                a0 = __builtin_amdgcn_mfma_f32_16x16x32_f16(af, bfrag[0][kk], a0, 0, 0, 0);
                a1 = __builtin_amdgcn_mfma_f32_16x16x32_f16(af, bfrag[1][kk], a1, 0, 0, 0);
            }
            if (s & 1) {
                #pragma unroll
                for (int r = 0; r < 4; ++r) { ssum2 += a0[r] * a0[r]; ssum3 += a1[r] * a1[r]; }
            } else {
                #pragma unroll
                for (int r = 0; r < 4; ++r) { ssum0 += a0[r] * a0[r]; ssum1 += a1[r] * a1[r]; }
            }
        }
        __builtin_amdgcn_s_setprio(0);
    };

    // ---- pipeline: fold(0); loads(1); [MFMA(0) | ... ] ----
    fold_phase(0);
    issue_loads(1);
    asm volatile("s_waitcnt lgkmcnt(0)" ::: "memory");
    __builtin_amdgcn_s_barrier();
    asm volatile("" ::: "memory");

    mfma_phase();                                        // phase 0
    asm volatile("s_waitcnt lgkmcnt(0)" ::: "memory");   // ds_reads drained
    __builtin_amdgcn_s_barrier();
    asm volatile("" ::: "memory");

    fold_phase(1);
    issue_loads(2);
    asm volatile("s_waitcnt lgkmcnt(0)" ::: "memory");
    __builtin_amdgcn_s_barrier();
    asm volatile("" ::: "memory");

    mfma_phase();                                        // phase 1
    asm volatile("s_waitcnt lgkmcnt(0)" ::: "memory");
    __builtin_amdgcn_s_barrier();
    asm volatile("" ::: "memory");

    fold_phase(2);
    asm volatile("s_waitcnt lgkmcnt(0)" ::: "memory");
    __builtin_amdgcn_s_barrier();
    asm volatile("" ::: "memory");

    mfma_phase();                                        // phase 2

    // ---- reduce over k-groups (D col = lane&15); one owner wave per comp ----
    {
        float v = ssum0 + ssum2;
        v += __shfl_xor(v, 16, 64);
        v += __shfl_xor(v, 32, 64);
        if (kg == 0) scol[is_sin * 128 + (cq & 3) * 32 + r16] = v;
        float w = ssum1 + ssum3;
        w += __shfl_xor(w, 16, 64);
        w += __shfl_xor(w, 32, 64);
        if (kg == 0) scol[is_sin * 128 + (cq & 3) * 32 + 16 + r16] = w;
    }
    __syncthreads();
    if (tid < NB) {
        out[(size_t)row * NB + tid] = (scol[tid] + scol[tid + NB]) * (1.0f / 257.0f);
    }
}

extern "C" void kernel_launch(void* const* d_in, const int* in_sizes, int n_in,
                              void* d_out, int out_size, void* d_ws, size_t ws_size,
                              hipStream_t stream) {
    const float* X = (const float*)d_in[0];
    float* out = (float*)d_out;
    f16* bt = (f16*)d_ws;   // 64 KB basis table
    (void)in_sizes; (void)n_in; (void)ws_size; (void)out_size;
    basis_kernel<<<dim3(16), dim3(256), 0, stream>>>(bt);
    psd_kernel<<<dim3(NROWS), dim3(512), 0, stream>>>(X, bt, out);
}

// Round 15
// 57.209 us; speedup vs baseline: 1.5023x; 1.5023x over previous
//
#include <hip/hip_runtime.h>
#include <hip/hip_bf16.h>

#define NS     32768
#define NROWS  2048
#define HOP    127
#define NW     257
#define NB     128
#define WTILE  16
#define NT     17            // sub-tiles of 16 windows; sub-tile 16 has 1 valid window
#define TWOPI_255 0.02463994236f   // 2*pi/255

typedef _Float16 f16;
typedef __attribute__((ext_vector_type(2))) _Float16 f16x2;
typedef __attribute__((ext_vector_type(4))) _Float16 f16x4;
typedef __attribute__((ext_vector_type(8))) _Float16 f16x8;
typedef __attribute__((ext_vector_type(4))) float f32x4;

__device__ inline f32x4 load4u(const char* p) {  // 4B-aligned 16B load
    f32x4 v;
    __builtin_memcpy(&v, p, 16);
    return v;
}

// ---------------------------------------------------------------------------
// Kernel 1: folded-DFT basis table (64 KB) in fragment order (as round 8).
// ---------------------------------------------------------------------------
__global__ __launch_bounds__(256)
void basis_kernel(f16* __restrict__ bt) {
    const int t  = blockIdx.x * 256 + threadIdx.x;   // 0..4095
    const int fi = t >> 6;
    const int l  = t & 63;
    const int cq = fi >> 3;
    const int nt = (fi >> 2) & 1;
    const int kk = fi & 3;
    const int is_sin = cq >> 2;
    const int f  = (cq & 3) * 32 + nt * 16 + (l & 15);   // freq 0..127
    int m = (f * (kk * 32 + (l >> 4) * 8)) % 255;
    f16x8 v;
    #pragma unroll
    for (int j = 0; j < 8; ++j) {
        const float ang = (float)m * TWOPI_255;
        v[j] = (f16)(is_sin ? __sinf(ang) : __cosf(ang));
        m += f; if (m >= 255) m -= 255;
    }
    *(f16x8*)(bt + (size_t)t * 8) = v;   // 16B/thread, coalesced
}

// ---------------------------------------------------------------------------
// Kernel 2: one block (8 waves, 512 thr) per row; wave cq owns 32 comps
// (bfrag = 32 VGPR; (512,6) -> ~84 VGPR cap, 3 blocks = 24 waves/CU — the
// proven-best operating point; r9/r12 showed both occupancy directions lose).
// QUAD-buffered 16-window sub-tiles, barrier every OTHER sub-tile (9 total);
// buffer reuse distance 4 always spans >=1 barrier. Fine-grained interleave
// (MFMA | fold | load-issue per iteration) — r11/r13/r14 showed every
// coarser/burstier schedule regresses. No setprio: m190-style lockstep waves.
// K folded 255->128: y+[k]=x[k]+x[255-k] (cos), y-[k]=x[k]-x[255-k] (sin).
// S[f] = (sum_w Ccos^2 + Csin^2)/257.
// ---------------------------------------------------------------------------
__global__ __launch_bounds__(512, 6)
void psd_kernel(const float* __restrict__ X, const f16* __restrict__ bt,
                float* __restrict__ out) {
    const int row  = blockIdx.x;
    const int tid  = threadIdx.x;
    const int lane = tid & 63;
    const int cq   = tid >> 6;      // wave 0..7
    const int r16  = lane & 15;
    const int kg   = lane >> 4;
    const int is_sin = cq >> 2;     // waves 4..7 -> sin half

    __shared__ alignas(16) f16 atile[4][WTILE * 256];  // 4 x 8 KB, XOR-swizzled
    __shared__ float scol[256];

    const char* __restrict__ xrow = (const char*)(X + (size_t)row * NS);

    const int sw  = tid >> 5;           // staging window 0..15
    const int sq  = tid & 31;           // staging k-quad 0..31

    // loop-invariant per-lane global byte offsets (tile-local)
    const uint voff_f = (uint)((sw * HOP + sq * 4) * 4);
    const uint voff_r = (uint)((sw * HOP + 252 - sq * 4) * 4);
    const uint vclamp = (uint)((NS - 4) * 4);   // max safe 16B-load byte offset

    // ---- sub-tile-0 staging loads ----
    f32x4 fv = load4u(xrow + voff_f);
    f32x4 rv = load4u(xrow + voff_r);

    // ---- basis fragments: 8 coalesced dwordx4 (table L2-resident) ----
    f16x8 bfrag[2][4];
    {
        const char* bp = (const char*)bt + (uint)(cq * 8192 + lane * 16);
        #pragma unroll
        for (int nt = 0; nt < 2; ++nt)
            #pragma unroll
            for (int kk = 0; kk < 4; ++kk)
                bfrag[nt][kk] = *(const f16x8*)(bp + (uint)((nt * 4 + kk) * 1024));
    }

    char* const lds = (char*)&atile[0][0];

    // hoisted LDS byte offsets (rd derived by XOR: base bits 6-7 zero, swizzle
    // has no bit 7, so base^(kk<<6)^rswz == (base+kk*64)^rswz)
    const uint swz  = (uint)((sw & 7) << 4);
    const uint wr_p = ((uint)(sw * 512 + sq * 8)) ^ swz;         // y+ (8B)
    const uint wr_m = ((uint)(sw * 512 + sq * 8 + 256)) ^ swz;   // y- (8B)
    const uint rd0  = ((uint)(r16 * 512 + is_sin * 256 + kg * 16))
                    ^ ((uint)((r16 & 7) << 4));

    // ---- packed fold (4 pairs) + 2 x ds_write_b64 ----
    auto fold_write = [&](char* wp, bool valid) {
        // partner of k=sq*4+j is rv[3-j]
        const f16x2 fp01 = __builtin_bit_cast(f16x2, __builtin_amdgcn_cvt_pkrtz(fv[0], fv[1]));
        const f16x2 fp23 = __builtin_bit_cast(f16x2, __builtin_amdgcn_cvt_pkrtz(fv[2], fv[3]));
        const f16x2 rp01 = __builtin_bit_cast(f16x2, __builtin_amdgcn_cvt_pkrtz(rv[3], rv[2]));
        const f16x2 rp23 = __builtin_bit_cast(f16x2, __builtin_amdgcn_cvt_pkrtz(rv[1], rv[0]));
        const f16x2 yp01 = fp01 + rp01, yp23 = fp23 + rp23;
        const f16x2 ym01 = fp01 - rp01, ym23 = fp23 - rp23;
        f16x4 h0, h1;
        h0[0] = yp01[0]; h0[1] = yp01[1]; h0[2] = yp23[0]; h0[3] = yp23[1];
        h1[0] = ym01[0]; h1[1] = ym01[1]; h1[2] = ym23[0]; h1[3] = ym23[1];
        if (sq == 0) { h0[0] = (f16)fv[0]; h1[0] = (f16)0.0f; }  // k=0: pad partner
        if (!valid) {
            #pragma unroll
            for (int j = 0; j < 4; ++j) { h0[j] = (f16)0.0f; h1[j] = (f16)0.0f; }
        }
        *(f16x4*)(wp + wr_p) = h0;
        *(f16x4*)(wp + wr_m) = h1;
    };

    // ---- prologue: fold st0, st1; issue st2 loads; one barrier ----
    fold_write(lds + (0 << 13), true);
    {
        const uint tb = (uint)(1 * WTILE * HOP * 4);
        fv = load4u(xrow + (voff_f + tb));
        rv = load4u(xrow + (voff_r + tb));
    }
    fold_write(lds + (1 << 13), true);
    {
        const uint tb = (uint)(2 * WTILE * HOP * 4);
        fv = load4u(xrow + (voff_f + tb));
        rv = load4u(xrow + (voff_r + tb));
    }
    asm volatile("s_waitcnt lgkmcnt(0)" ::: "memory");
    __builtin_amdgcn_s_barrier();
    asm volatile("" ::: "memory");

    float ssum0 = 0.f, ssum1 = 0.f;

    // iter mt: MFMA st=mt from buf[mt&3]; fold st=mt+2 -> buf[(mt+2)&3];
    // issue loads st=mt+3; barrier after odd iters only.
    for (int mt = 0; mt < NT; ++mt) {
        const char* ap = lds + ((mt & 3) << 13);

        f32x4 acc0 = {0,0,0,0}, acc1 = {0,0,0,0};
        #pragma unroll
        for (int kk = 0; kk < 4; ++kk) {
            const f16x8 af = *(const f16x8*)(ap + (rd0 ^ (uint)(kk << 6)));
            acc0 = __builtin_amdgcn_mfma_f32_16x16x32_f16(af, bfrag[0][kk], acc0, 0, 0, 0);
            acc1 = __builtin_amdgcn_mfma_f32_16x16x32_f16(af, bfrag[1][kk], acc1, 0, 0, 0);
        }
        #pragma unroll
        for (int r = 0; r < 4; ++r) {
            ssum0 += acc0[r] * acc0[r];
            ssum1 += acc1[r] * acc1[r];
        }

        if (mt + 2 < NT) {
            // fold+write sub-tile mt+2 (loads issued one iteration ago)
            char* wp = lds + (((mt + 2) & 3) << 13);
            const bool valid = (mt + 2 != 16) || (sw == 0);  // st16: only window 256
            fold_write(wp, valid);
            if (mt + 3 < NT) {   // issue loads for st=mt+3; in flight across barrier
                const uint tb = (uint)((mt + 3) * WTILE * HOP * 4);
                fv = load4u(xrow + min(voff_f + tb, vclamp));
                rv = load4u(xrow + min(voff_r + tb, vclamp));
            }
        }
        if (mt & 1) {
            asm volatile("s_waitcnt lgkmcnt(0)" ::: "memory");  // drain ds ops only
            __builtin_amdgcn_s_barrier();
            asm volatile("" ::: "memory");
        }
    }

    // ---- reduce over k-groups (D col = lane&15); one owner wave per comp ----
    {
        float v = ssum0;
        v += __shfl_xor(v, 16, 64);
        v += __shfl_xor(v, 32, 64);
        if (kg == 0) scol[is_sin * 128 + (cq & 3) * 32 + r16] = v;
        float w = ssum1;
        w += __shfl_xor(w, 16, 64);
        w += __shfl_xor(w, 32, 64);
        if (kg == 0) scol[is_sin * 128 + (cq & 3) * 32 + 16 + r16] = w;
    }
    __syncthreads();
    if (tid < NB) {
        out[(size_t)row * NB + tid] = (scol[tid] + scol[tid + NB]) * (1.0f / 257.0f);
    }
}

extern "C" void kernel_launch(void* const* d_in, const int* in_sizes, int n_in,
                              void* d_out, int out_size, void* d_ws, size_t ws_size,
                              hipStream_t stream) {
    const float* X = (const float*)d_in[0];
    float* out = (float*)d_out;
    f16* bt = (f16*)d_ws;   // 64 KB basis table
    (void)in_sizes; (void)n_in; (void)ws_size; (void)out_size;
    basis_kernel<<<dim3(16), dim3(256), 0, stream>>>(bt);
    psd_kernel<<<dim3(NROWS), dim3(512), 0, stream>>>(X, bt, out);
}

// Round 16
// 53.803 us; speedup vs baseline: 1.5974x; 1.0633x over previous
//
#include <hip/hip_runtime.h>
#include <hip/hip_bf16.h>

#define NS     32768
#define NROWS  2048
#define HOP    127
#define NW     257
#define NB     128
#define WTILE  16
#define NT     17            // sub-tiles of 16 windows; sub-tile 16 has 1 valid window
#define TWOPI_255 0.02463994236f   // 2*pi/255

typedef _Float16 f16;
typedef __attribute__((ext_vector_type(2))) _Float16 f16x2;
typedef __attribute__((ext_vector_type(4))) _Float16 f16x4;
typedef __attribute__((ext_vector_type(8))) _Float16 f16x8;
typedef __attribute__((ext_vector_type(4))) float f32x4;

__device__ inline f32x4 load4u(const char* p) {  // 4B-aligned 16B load
    f32x4 v;
    __builtin_memcpy(&v, p, 16);
    return v;
}

// ---------------------------------------------------------------------------
// Kernel 1: folded-DFT basis table (64 KB) in fragment order.
// Fragment fi: comp = (fi>>5)*128 + ((fi>>3)&3)*32 + ((fi>>2)&1)*16 + (l&15),
// k = (fi&3)*32 + (l>>4)*8 + j. Row-independent; shared by all blocks.
// ---------------------------------------------------------------------------
__global__ __launch_bounds__(256)
void basis_kernel(f16* __restrict__ bt) {
    const int t  = blockIdx.x * 256 + threadIdx.x;   // 0..4095
    const int fi = t >> 6;
    const int l  = t & 63;
    const int cq = fi >> 3;
    const int nt = (fi >> 2) & 1;
    const int kk = fi & 3;
    const int is_sin = cq >> 2;
    const int f  = (cq & 3) * 32 + nt * 16 + (l & 15);   // freq 0..127
    int m = (f * (kk * 32 + (l >> 4) * 8)) % 255;
    f16x8 v;
    #pragma unroll
    for (int j = 0; j < 8; ++j) {
        const float ang = (float)m * TWOPI_255;
        v[j] = (f16)(is_sin ? __sinf(ang) : __cosf(ang));
        m += f; if (m >= 255) m -= 255;
    }
    *(f16x8*)(bt + (size_t)t * 8) = v;   // 16B/thread, coalesced
}

// ---------------------------------------------------------------------------
// Kernel 2: one block (8 waves, 512 thr) per row; wave cq owns 32 comps
// (bfrag = 32 VGPR -> ~68 VGPR total, 3 blocks = 24 waves/CU, the proven-best
// operating point; r9/r12 showed both occupancy directions lose; r11/r13/r14
// showed coarser/burstier schedules lose; r15 showed setprio is +7%).
// QUAD-buffered 16-window sub-tiles, barrier every OTHER sub-tile (9 total);
// buffer reuse distance 4 always spans >=1 barrier.
// K folded 255->128: y+[k]=x[k]+x[255-k] (cos), y-[k]=x[k]-x[255-k] (sin).
// S[f] = (sum_w Ccos^2 + Csin^2)/257.
// ---------------------------------------------------------------------------
__global__ __launch_bounds__(512, 6)
void psd_kernel(const float* __restrict__ X, const f16* __restrict__ bt,
                float* __restrict__ out) {
    const int row  = blockIdx.x;
    const int tid  = threadIdx.x;
    const int lane = tid & 63;
    const int cq   = tid >> 6;      // wave 0..7
    const int r16  = lane & 15;
    const int kg   = lane >> 4;
    const int is_sin = cq >> 2;     // waves 4..7 -> sin half

    __shared__ alignas(16) f16 atile[4][WTILE * 256];  // 4 x 8 KB, XOR-swizzled
    __shared__ float scol[256];

    const char* __restrict__ xrow = (const char*)(X + (size_t)row * NS);

    const int sw  = tid >> 5;           // staging window 0..15
    const int sq  = tid & 31;           // staging k-quad 0..31

    // loop-invariant per-lane global byte offsets (tile-local)
    const uint voff_f = (uint)((sw * HOP + sq * 4) * 4);
    const uint voff_r = (uint)((sw * HOP + 252 - sq * 4) * 4);
    const uint vclamp = (uint)((NS - 4) * 4);   // max safe 16B-load byte offset

    // ---- sub-tile-0 staging loads ----
    f32x4 fv = load4u(xrow + voff_f);
    f32x4 rv = load4u(xrow + voff_r);

    // ---- basis fragments: 8 coalesced dwordx4 (table L2-resident) ----
    f16x8 bfrag[2][4];
    {
        const char* bp = (const char*)bt + (uint)(cq * 8192 + lane * 16);
        #pragma unroll
        for (int nt = 0; nt < 2; ++nt)
            #pragma unroll
            for (int kk = 0; kk < 4; ++kk)
                bfrag[nt][kk] = *(const f16x8*)(bp + (uint)((nt * 4 + kk) * 1024));
    }

    char* const lds = (char*)&atile[0][0];

    // hoisted LDS byte offsets (rd derived by XOR: base bits 6-7 zero, swizzle
    // has no bit 7, so base^(kk<<6)^rswz == (base+kk*64)^rswz)
    const uint swz  = (uint)((sw & 7) << 4);
    const uint wr_p = ((uint)(sw * 512 + sq * 8)) ^ swz;         // y+ (8B)
    const uint wr_m = ((uint)(sw * 512 + sq * 8 + 256)) ^ swz;   // y- (8B)
    const uint rd0  = ((uint)(r16 * 512 + is_sin * 256 + kg * 16))
                    ^ ((uint)((r16 & 7) << 4));

    // ---- packed fold (4 pairs) + 2 x ds_write_b64 ----
    auto fold_write = [&](char* wp, bool valid) {
        // partner of k=sq*4+j is rv[3-j]
        const f16x2 fp01 = __builtin_bit_cast(f16x2, __builtin_amdgcn_cvt_pkrtz(fv[0], fv[1]));
        const f16x2 fp23 = __builtin_bit_cast(f16x2, __builtin_amdgcn_cvt_pkrtz(fv[2], fv[3]));
        const f16x2 rp01 = __builtin_bit_cast(f16x2, __builtin_amdgcn_cvt_pkrtz(rv[3], rv[2]));
        const f16x2 rp23 = __builtin_bit_cast(f16x2, __builtin_amdgcn_cvt_pkrtz(rv[1], rv[0]));
        const f16x2 yp01 = fp01 + rp01, yp23 = fp23 + rp23;
        const f16x2 ym01 = fp01 - rp01, ym23 = fp23 - rp23;
        f16x4 h0, h1;
        h0[0] = yp01[0]; h0[1] = yp01[1]; h0[2] = yp23[0]; h0[3] = yp23[1];
        h1[0] = ym01[0]; h1[1] = ym01[1]; h1[2] = ym23[0]; h1[3] = ym23[1];
        if (sq == 0) { h0[0] = (f16)fv[0]; h1[0] = (f16)0.0f; }  // k=0: pad partner
        if (!valid) {
            #pragma unroll
            for (int j = 0; j < 4; ++j) { h0[j] = (f16)0.0f; h1[j] = (f16)0.0f; }
        }
        *(f16x4*)(wp + wr_p) = h0;
        *(f16x4*)(wp + wr_m) = h1;
    };

    // ---- prologue: fold st0, st1; issue st2 loads; one barrier ----
    fold_write(lds + (0 << 13), true);
    {
        const uint tb = (uint)(1 * WTILE * HOP * 4);
        fv = load4u(xrow + (voff_f + tb));
        rv = load4u(xrow + (voff_r + tb));
    }
    fold_write(lds + (1 << 13), true);
    {
        const uint tb = (uint)(2 * WTILE * HOP * 4);
        fv = load4u(xrow + (voff_f + tb));
        rv = load4u(xrow + (voff_r + tb));
    }
    asm volatile("s_waitcnt lgkmcnt(0)" ::: "memory");
    __builtin_amdgcn_s_barrier();
    asm volatile("" ::: "memory");

    float ssum0 = 0.f, ssum1 = 0.f;

    // iter mt: MFMA st=mt from buf[mt&3]; fold st=mt+2 -> buf[(mt+2)&3];
    // issue loads st=mt+3; barrier after odd iters only.
    for (int mt = 0; mt < NT; ++mt) {
        const char* ap = lds + ((mt & 3) << 13);

        f32x4 acc0 = {0,0,0,0}, acc1 = {0,0,0,0};
        __builtin_amdgcn_s_setprio(1);
        #pragma unroll
        for (int kk = 0; kk < 4; ++kk) {
            const f16x8 af = *(const f16x8*)(ap + (rd0 ^ (uint)(kk << 6)));
            acc0 = __builtin_amdgcn_mfma_f32_16x16x32_f16(af, bfrag[0][kk], acc0, 0, 0, 0);
            acc1 = __builtin_amdgcn_mfma_f32_16x16x32_f16(af, bfrag[1][kk], acc1, 0, 0, 0);
        }
        __builtin_amdgcn_s_setprio(0);
        #pragma unroll
        for (int r = 0; r < 4; ++r) {
            ssum0 += acc0[r] * acc0[r];
            ssum1 += acc1[r] * acc1[r];
        }

        if (mt + 2 < NT) {
            // fold+write sub-tile mt+2 (loads issued one iteration ago)
            char* wp = lds + (((mt + 2) & 3) << 13);
            const bool valid = (mt + 2 != 16) || (sw == 0);  // st16: only window 256
            fold_write(wp, valid);
            if (mt + 3 < NT) {   // issue loads for st=mt+3; in flight across barrier
                const uint tb = (uint)((mt + 3) * WTILE * HOP * 4);
                fv = load4u(xrow + min(voff_f + tb, vclamp));
                rv = load4u(xrow + min(voff_r + tb, vclamp));
            }
        }
        if (mt & 1) {
            asm volatile("s_waitcnt lgkmcnt(0)" ::: "memory");  // drain ds ops only
            __builtin_amdgcn_s_barrier();
            asm volatile("" ::: "memory");
        }
    }

    // ---- reduce over k-groups (D col = lane&15); one owner wave per comp ----
    {
        float v = ssum0;
        v += __shfl_xor(v, 16, 64);
        v += __shfl_xor(v, 32, 64);
        if (kg == 0) scol[is_sin * 128 + (cq & 3) * 32 + r16] = v;
        float w = ssum1;
        w += __shfl_xor(w, 16, 64);
        w += __shfl_xor(w, 32, 64);
        if (kg == 0) scol[is_sin * 128 + (cq & 3) * 32 + 16 + r16] = w;
    }
    __syncthreads();
    if (tid < NB) {
        out[(size_t)row * NB + tid] = (scol[tid] + scol[tid + NB]) * (1.0f / 257.0f);
    }
}

extern "C" void kernel_launch(void* const* d_in, const int* in_sizes, int n_in,
                              void* d_out, int out_size, void* d_ws, size_t ws_size,
                              hipStream_t stream) {
    const float* X = (const float*)d_in[0];
    float* out = (float*)d_out;
    f16* bt = (f16*)d_ws;   // 64 KB basis table
    (void)in_sizes; (void)n_in; (void)ws_size; (void)out_size;
    basis_kernel<<<dim3(16), dim3(256), 0, stream>>>(bt);
    psd_kernel<<<dim3(NROWS), dim3(512), 0, stream>>>(X, bt, out);
}